// Round 1
// baseline (247.311 us; speedup 1.0000x reference)
//
#include <hip/hip_runtime.h>

#define IMG_H 384
#define IMG_W 384
#define NIMG  64
#define TILE  32
#define HALO  5
#define LTS   (TILE + 2*HALO)   // 42

__global__ __launch_bounds__(256) void boundary_bce_fused(
    const float* __restrict__ hand,
    const float* __restrict__ obj,
    const float* __restrict__ target,
    float* __restrict__ accum)
{
    __shared__ float hA[LTS*LTS], hB[LTS*LTS];
    __shared__ float oA[LTS*LTS], oB[LTS*LTS];

    const int tid = threadIdx.x;
    const int tx = blockIdx.x, ty = blockIdx.y, n = blockIdx.z;
    const int x0 = tx*TILE - HALO, y0 = ty*TILE - HALO;

    const float* __restrict__ hp = hand   + (size_t)n*IMG_H*IMG_W;
    const float* __restrict__ op = obj    + (size_t)n*IMG_H*IMG_W;
    const float* __restrict__ tp = target + (size_t)n*IMG_H*IMG_W;

    // ---- load 42x42 halo tile (zeros outside image) ----
    for (int i = tid; i < LTS*LTS; i += 256) {
        int ly = i / LTS, lx = i - ly*LTS;
        int gy = y0 + ly, gx = x0 + lx;
        bool in = (gy >= 0) & (gy < IMG_H) & (gx >= 0) & (gx < IMG_W);
        size_t gidx = (size_t)gy*IMG_W + gx;
        hA[i] = in ? hp[gidx] : 0.f;
        oA[i] = in ? op[gidx] : 0.f;
    }
    __syncthreads();

    // ---- 5 fused dilation iterations (ping-pong) ----
    float* hsrc = hA; float* hdst = hB;
    float* osrc = oA; float* odst = oB;
    #pragma unroll
    for (int it = 0; it < 5; ++it) {
        // compute interior [1..40]^2 ; validity ring analysis guarantees
        // the final [5..36]^2 output region is exact after 5 iters.
        for (int i = tid; i < 40*40; i += 256) {
            int ry = i / 40, rx = i - ry*40;
            int ly = ry + 1, lx = rx + 1;
            int idx = ly*LTS + lx;
            int gy = y0 + ly, gx = x0 + lx;
            // reference re-applies zero padding every conv: out-of-image
            // cells stay 0 at every iteration.
            bool in = (gy >= 0) & (gy < IMG_H) & (gx >= 0) & (gx < IMG_W);
            float hs = hsrc[idx] + hsrc[idx-1] + hsrc[idx+1]
                     + hsrc[idx-LTS] + hsrc[idx+LTS];
            float os = osrc[idx] + osrc[idx-1] + osrc[idx+1]
                     + osrc[idx-LTS] + osrc[idx+LTS];
            hdst[idx] = in ? fminf(hs, 1.f) : 0.f;
            odst[idx] = in ? fminf(os, 1.f) : 0.f;
        }
        __syncthreads();
        float* t;
        t = hsrc; hsrc = hdst; hdst = t;
        t = osrc; osrc = odst; odst = t;
    }

    // ---- BCE over the 32x32 output region, local coords [5..36] ----
    float psum = 0.f;
    for (int i = tid; i < TILE*TILE; i += 256) {
        int ry = i / TILE, rx = i - ry*TILE;
        int ly = ry + HALO, lx = rx + HALO;
        float h = hsrc[ly*LTS + lx];
        float o = osrc[ly*LTS + lx];
        float p = h * o;                       // in [0,1]
        float lp  = fmaxf(logf(p),       -100.f);
        float l1p = fmaxf(logf(1.f - p), -100.f);
        int gy = y0 + ly, gx = x0 + lx;
        float t = tp[(size_t)gy*IMG_W + gx];
        psum += t*lp + (1.f - t)*l1p;
    }

    // ---- block reduction: wave shuffle -> cross-wave LDS -> atomic ----
    #pragma unroll
    for (int off = 32; off > 0; off >>= 1)
        psum += __shfl_down(psum, off, 64);

    __shared__ float wsum[4];
    if ((tid & 63) == 0) wsum[tid >> 6] = psum;
    __syncthreads();
    if (tid == 0) {
        float s = wsum[0] + wsum[1] + wsum[2] + wsum[3];
        atomicAdd(accum, s);
    }
}

__global__ void boundary_bce_finalize(const float* __restrict__ accum,
                                      float* __restrict__ out)
{
    const float inv_count = 1.0f / ((float)NIMG * IMG_H * IMG_W);
    out[0] = -accum[0] * inv_count;
}

extern "C" void kernel_launch(void* const* d_in, const int* in_sizes, int n_in,
                              void* d_out, int out_size, void* d_ws, size_t ws_size,
                              hipStream_t stream)
{
    const float* hand   = (const float*)d_in[0];
    const float* obj    = (const float*)d_in[1];
    const float* target = (const float*)d_in[2];
    float* accum = (float*)d_ws;

    hipMemsetAsync(accum, 0, sizeof(float), stream);

    dim3 grid(IMG_W / TILE, IMG_H / TILE, NIMG);   // 12 x 12 x 64
    boundary_bce_fused<<<grid, 256, 0, stream>>>(hand, obj, target, accum);
    boundary_bce_finalize<<<1, 1, 0, stream>>>(accum, (float*)d_out);
}

// Round 2
// 182.812 us; speedup vs baseline: 1.3528x; 1.3528x over previous
//
#include <hip/hip_runtime.h>

#define IMG   384
#define NIMG  64
#define HALO  5
#define TX    54            // valid columns per tile (64 - 2*HALO)
#define RW    26            // rows per wave (registers per mask per lane)
#define NW    4             // waves per block
#define TH    (NW*RW)       // 104 tile rows
#define VY    (TH - 2*HALO) // 94 valid rows per strip
#define GRIDX 8             // ceil(384/54)
#define GRIDY 5             // ceil(384/94)
#define NPART (GRIDX*GRIDY*NIMG)

// lane i <- lane i-1 (x-1 neighbor), lane 0 gets 0   (DPP WAVE_SHR1)
__device__ __forceinline__ float dpp_left(float x) {
    return __int_as_float(
        __builtin_amdgcn_update_dpp(0, __float_as_int(x), 0x138, 0xF, 0xF, true));
}
// lane i <- lane i+1 (x+1 neighbor), lane 63 gets 0  (DPP WAVE_SHL1)
__device__ __forceinline__ float dpp_right(float x) {
    return __int_as_float(
        __builtin_amdgcn_update_dpp(0, __float_as_int(x), 0x130, 0xF, 0xF, true));
}

__global__ __launch_bounds__(256) void boundary_bce_fused(
    const float* __restrict__ hand,
    const float* __restrict__ obj,
    const float* __restrict__ target,
    float* __restrict__ partial)
{
    const int tid  = threadIdx.x;
    const int lane = tid & 63;
    const int w    = tid >> 6;                 // wave id 0..3 (vertical strip)
    const int tx = blockIdx.x, ty = blockIdx.y, n = blockIdx.z;

    const int x0    = tx * TX - HALO;          // tile left (can be -5)
    const int y0    = ty * VY - HALO;          // tile top  (can be -5)
    const int gx    = x0 + lane;
    const int ybase = y0 + w * RW;

    const size_t ioff = (size_t)n * IMG * IMG;
    const float* __restrict__ hp = hand + ioff;
    const float* __restrict__ op = obj  + ioff;
    const float* __restrict__ tp = target + ioff;

    // per-lane register columns
    float h[RW], o[RW], m[RW];
    const bool colok = (gx >= 0) & (gx < IMG);

    #pragma unroll
    for (int r = 0; r < RW; ++r) {
        int gy = ybase + r;
        bool ok = colok & (gy >= 0) & (gy < IMG);
        m[r] = ok ? 1.f : 0.f;
        size_t idx = (size_t)gy * IMG + gx;
        h[r] = ok ? hp[idx] : 0.f;
        o[r] = ok ? op[idx] : 0.f;
    }

    // inter-wave vertical halo rows (old values), per mask
    __shared__ float topH[NW][64], botH[NW][64];
    __shared__ float topO[NW][64], botO[NW][64];

    #pragma unroll 1
    for (int it = 0; it < 5; ++it) {
        // publish OLD boundary rows
        topH[w][lane] = h[0];      botH[w][lane] = h[RW-1];
        topO[w][lane] = o[0];      botO[w][lane] = o[RW-1];
        __syncthreads();

        float aboveH = (w > 0)      ? botH[w-1][lane] : 0.f;
        float aboveO = (w > 0)      ? botO[w-1][lane] : 0.f;
        float belowH = (w < NW - 1) ? topH[w+1][lane] : 0.f;
        float belowO = (w < NW - 1) ? topO[w+1][lane] : 0.f;

        float prevH = aboveH, prevO = aboveO;
        #pragma unroll
        for (int r = 0; r < RW; ++r) {
            float dnH = (r == RW - 1) ? belowH : h[r+1];
            float dnO = (r == RW - 1) ? belowO : o[r+1];
            float cH = h[r], cO = o[r];
            float sH = cH + dpp_left(cH) + dpp_right(cH) + prevH + dnH;
            float sO = cO + dpp_left(cO) + dpp_right(cO) + prevO + dnO;
            h[r] = fminf(sH, 1.f) * m[r];   // re-apply zero padding each conv
            o[r] = fminf(sO, 1.f) * m[r];
            prevH = cH; prevO = cO;
        }
        __syncthreads();   // reads done before next iteration's halo writes
    }

    // BCE over the valid region: lane in [5,58], local row in [5,98], in-image
    float psum = 0.f;
    const bool laneok = (lane >= HALO) & (lane <= 63 - HALO) & (gx < IMG);
    #pragma unroll
    for (int r = 0; r < RW; ++r) {
        int ly = w * RW + r;
        int gy = ybase + r;
        bool valid = laneok & (ly >= HALO) & (ly <= TH - 1 - HALO) & (gy < IMG);
        if (valid) {
            float p  = h[r] * o[r];
            float t  = tp[(size_t)gy * IMG + gx];
            float lp  = fmaxf(__logf(p),       -100.f);
            float l1p = fmaxf(__logf(1.f - p), -100.f);
            psum += t * lp + (1.f - t) * l1p;
        }
    }

    // block reduction -> one partial per block (no memset needed)
    #pragma unroll
    for (int off = 32; off > 0; off >>= 1)
        psum += __shfl_down(psum, off, 64);
    __shared__ float wsum[NW];
    if (lane == 0) wsum[w] = psum;
    __syncthreads();
    if (tid == 0) {
        partial[blockIdx.x + GRIDX * (blockIdx.y + GRIDY * blockIdx.z)] =
            wsum[0] + wsum[1] + wsum[2] + wsum[3];
    }
}

__global__ __launch_bounds__(256) void boundary_bce_finalize(
    const float* __restrict__ partial, float* __restrict__ out)
{
    float s = 0.f;
    for (int i = threadIdx.x; i < NPART; i += 256) s += partial[i];
    #pragma unroll
    for (int off = 32; off > 0; off >>= 1)
        s += __shfl_down(s, off, 64);
    __shared__ float ws[4];
    if ((threadIdx.x & 63) == 0) ws[threadIdx.x >> 6] = s;
    __syncthreads();
    if (threadIdx.x == 0) {
        float tot = ws[0] + ws[1] + ws[2] + ws[3];
        out[0] = -tot / (float)((size_t)NIMG * IMG * IMG);
    }
}

extern "C" void kernel_launch(void* const* d_in, const int* in_sizes, int n_in,
                              void* d_out, int out_size, void* d_ws, size_t ws_size,
                              hipStream_t stream)
{
    const float* hand   = (const float*)d_in[0];
    const float* obj    = (const float*)d_in[1];
    const float* target = (const float*)d_in[2];
    float* partial = (float*)d_ws;   // NPART floats; every slot written each call

    dim3 grid(GRIDX, GRIDY, NIMG);   // 8 x 5 x 64 = 2560 blocks
    boundary_bce_fused<<<grid, 256, 0, stream>>>(hand, obj, target, partial);
    boundary_bce_finalize<<<1, 256, 0, stream>>>(partial, (float*)d_out);
}

// Round 3
// 169.139 us; speedup vs baseline: 1.4622x; 1.0808x over previous
//
#include <hip/hip_runtime.h>

#define IMG   384
#define NIMG  64
#define HALO  5
#define NW    4                 // waves per block (vertical)
#define RW    22                // rows per wave
#define TH    (NW*RW)           // 88 tile rows
#define VY    (TH - 2*HALO)     // 78 valid rows per strip
#define VX    116               // valid cols per tile (x0 stays even)
#define GRIDX 4                 // 4*116 = 464 >= 384
#define GRIDY 5                 // 5*78  = 390 >= 384
#define NPART (GRIDX*GRIDY*NIMG)

typedef float f32x2 __attribute__((ext_vector_type(2)));

static __device__ __forceinline__ f32x2 pk_add(f32x2 a, f32x2 b) {
    f32x2 d; asm("v_pk_add_f32 %0, %1, %2" : "=v"(d) : "v"(a), "v"(b)); return d;
}
// d.lo = a.lo + b.hi ; d.hi = a.hi + b.lo   (within-pair horizontal terms)
static __device__ __forceinline__ f32x2 pk_add_swap(f32x2 a, f32x2 b) {
    f32x2 d; asm("v_pk_add_f32 %0, %1, %2 op_sel:[0,1] op_sel_hi:[1,0]"
                 : "=v"(d) : "v"(a), "v"(b)); return d;
}
static __device__ __forceinline__ f32x2 pk_mul(f32x2 a, f32x2 b) {
    f32x2 d; asm("v_pk_mul_f32 %0, %1, %2" : "=v"(d) : "v"(a), "v"(b)); return d;
}
// lane i <- lane i-1, lane 0 gets 0 (WAVE_SHR1)
static __device__ __forceinline__ float dpp_sr1(float x) {
    return __int_as_float(
        __builtin_amdgcn_update_dpp(0, __float_as_int(x), 0x138, 0xF, 0xF, true));
}
// lane i <- lane i+1, lane 63 gets 0 (WAVE_SHL1)
static __device__ __forceinline__ float dpp_sl1(float x) {
    return __int_as_float(
        __builtin_amdgcn_update_dpp(0, __float_as_int(x), 0x130, 0xF, 0xF, true));
}

__global__ __launch_bounds__(256) void boundary_bce_fused(
    const float* __restrict__ hand,
    const float* __restrict__ obj,
    const float* __restrict__ target,
    float* __restrict__ partial)
{
    const int tid  = threadIdx.x;
    const int lane = tid & 63;
    const int w    = tid >> 6;
    const int tx = blockIdx.x, ty = blockIdx.y, n = blockIdx.z;

    const int x0    = tx * VX - 6;          // even -> 8B-aligned pair loads
    const int y0    = ty * VY - HALO;
    const int gx0   = x0 + 2 * lane;        // this lane's column pair (gx0, gx0+1)
    const int ybase = y0 + w * RW;

    const size_t ioff = (size_t)n * IMG * IMG;
    const float* __restrict__ hp = hand   + ioff;
    const float* __restrict__ op = obj    + ioff;
    const float* __restrict__ tp = target + ioff;

    // IMG even & gx0 even => a pair is fully in-image or fully out.
    const bool colok = (gx0 >= 0) & (gx0 < IMG);
    const float mc   = colok ? 1.f : 0.f;
    const f32x2 mcol = {mc, mc};
    const f32x2 zero = {0.f, 0.f};

    f32x2 h[RW], o[RW];
    #pragma unroll
    for (int r = 0; r < RW; ++r) {
        int gy = ybase + r;
        bool ok = colok & (gy >= 0) & (gy < IMG);
        size_t idx = (size_t)gy * IMG + gx0;
        h[r] = ok ? *(const f32x2*)(hp + idx) : zero;
        o[r] = ok ? *(const f32x2*)(op + idx) : zero;
    }

    // Boundary-row zeroing: only rows gy==-1 and gy==IMG need forcing to 0
    // each iteration (junk beyond can never cross a zeroed row). With this
    // geometry they sit at constant register indices:
    //   ty==0:       gy=-1  -> tile row 4  -> w==0, r==4
    //   ty==GRIDY-1: gy=384 -> tile row 77 -> w==3, r==11   (y0=307)
    const bool ztop = (ty == 0)         && (w == 0);
    const bool zbot = (ty == GRIDY - 1) && (w == NW - 1);

    // inter-wave halo rows, double-buffered -> one barrier per iteration
    __shared__ f32x2 sTopH[2][NW][64], sBotH[2][NW][64];
    __shared__ f32x2 sTopO[2][NW][64], sBotO[2][NW][64];

    #pragma unroll 1
    for (int it = 0; it < 5; ++it) {
        const int b = it & 1;
        sTopH[b][w][lane] = h[0];  sBotH[b][w][lane] = h[RW-1];
        sTopO[b][w][lane] = o[0];  sBotO[b][w][lane] = o[RW-1];
        __syncthreads();

        f32x2 upH = (w > 0)      ? sBotH[b][w-1][lane] : zero;
        f32x2 upO = (w > 0)      ? sBotO[b][w-1][lane] : zero;
        f32x2 dnH = (w < NW - 1) ? sTopH[b][w+1][lane] : zero;
        f32x2 dnO = (w < NW - 1) ? sTopO[b][w+1][lane] : zero;

        f32x2 prevH = upH, prevO = upO;
        #pragma unroll
        for (int r = 0; r < RW; ++r) {
            f32x2 belowH = (r == RW - 1) ? dnH : h[r+1];
            f32x2 belowO = (r == RW - 1) ? dnO : o[r+1];
            f32x2 cH = h[r], cO = o[r];
            f32x2 vH = pk_add(pk_add(cH, prevH), belowH);   // vertical
            f32x2 vO = pk_add(pk_add(cO, prevO), belowO);
            f32x2 sH = pk_add_swap(vH, cH);                 // in-pair horizontal
            f32x2 sO = pk_add_swap(vO, cO);
            float plH = dpp_sr1(cH.y), nrH = dpp_sl1(cH.x); // cross-pair terms
            float plO = dpp_sr1(cO.y), nrO = dpp_sl1(cO.x);
            sH.x += plH; sH.y += nrH;
            sO.x += plO; sO.y += nrO;
            sH.x = fminf(sH.x, 1.f); sH.y = fminf(sH.y, 1.f);
            sO.x = fminf(sO.x, 1.f); sO.y = fminf(sO.y, 1.f);
            h[r] = pk_mul(sH, mcol);                        // col zero-padding
            o[r] = pk_mul(sO, mcol);
            prevH = cH; prevO = cO;
        }
        if (ztop) { h[4]  = zero; o[4]  = zero; }
        if (zbot) { h[11] = zero; o[11] = zero; }
        // no 2nd barrier: next iter writes the other LDS buffer
    }

    // ---- BCE over valid region: lanes 3..60, tile rows 5..82, gy < IMG ----
    float psum = 0.f;
    const bool lane_ok = colok & (lane >= 3) & (lane <= 60);
    #pragma unroll
    for (int r = 0; r < RW; ++r) {
        int ly = w * RW + r;
        int gy = ybase + r;
        bool v = lane_ok & (ly >= HALO) & (ly <= TH - 1 - HALO) & (gy < IMG);
        if (v) {
            f32x2 p = pk_mul(h[r], o[r]);
            f32x2 t = *(const f32x2*)(tp + (size_t)gy * IMG + gx0);
            float lp0  = fmaxf(__logf(p.x),       -100.f);
            float l1p0 = fmaxf(__logf(1.f - p.x), -100.f);
            float lp1  = fmaxf(__logf(p.y),       -100.f);
            float l1p1 = fmaxf(__logf(1.f - p.y), -100.f);
            psum += t.x * lp0 + (1.f - t.x) * l1p0;
            psum += t.y * lp1 + (1.f - t.y) * l1p1;
        }
    }

    #pragma unroll
    for (int off = 32; off > 0; off >>= 1)
        psum += __shfl_down(psum, off, 64);
    __shared__ float wsum[NW];
    if (lane == 0) wsum[w] = psum;
    __syncthreads();
    if (tid == 0) {
        partial[blockIdx.x + GRIDX * (blockIdx.y + GRIDY * blockIdx.z)] =
            wsum[0] + wsum[1] + wsum[2] + wsum[3];
    }
}

__global__ __launch_bounds__(256) void boundary_bce_finalize(
    const float* __restrict__ partial, float* __restrict__ out)
{
    float s = 0.f;
    for (int i = threadIdx.x; i < NPART; i += 256) s += partial[i];
    #pragma unroll
    for (int off = 32; off > 0; off >>= 1)
        s += __shfl_down(s, off, 64);
    __shared__ float ws[4];
    if ((threadIdx.x & 63) == 0) ws[threadIdx.x >> 6] = s;
    __syncthreads();
    if (threadIdx.x == 0) {
        float tot = ws[0] + ws[1] + ws[2] + ws[3];
        out[0] = -tot / (float)((size_t)NIMG * IMG * IMG);
    }
}

extern "C" void kernel_launch(void* const* d_in, const int* in_sizes, int n_in,
                              void* d_out, int out_size, void* d_ws, size_t ws_size,
                              hipStream_t stream)
{
    const float* hand   = (const float*)d_in[0];
    const float* obj    = (const float*)d_in[1];
    const float* target = (const float*)d_in[2];
    float* partial = (float*)d_ws;   // NPART floats, every slot written each call

    dim3 grid(GRIDX, GRIDY, NIMG);   // 4 x 5 x 64 = 1280 blocks
    boundary_bce_fused<<<grid, 256, 0, stream>>>(hand, obj, target, partial);
    boundary_bce_finalize<<<1, 256, 0, stream>>>(partial, (float*)d_out);
}